// Round 1
// baseline (383.470 us; speedup 1.0000x reference)
//
#include <hip/hip_runtime.h>
#include <hip/hip_fp16.h>

// Problem constants (fixed by setup_inputs): B=1, KVH=8, D=128, S=8192
#define HH 8
#define DD 128
#define SS 8192

typedef float f32x4 __attribute__((ext_vector_type(4)));

// Fused single-dispatch layout:
//   keys blocks : 1024  (one per (h, 64-wide s-tile))
//   vals blocks : 8192  (8 rows each)
//   attn blocks : 16384 (1024 float4 = 16 KB each)
// Interleaved 1:8:16 per 25-block group so HBM sees a uniform read+write mix
// for the whole dispatch instead of three serialized phases.
#define GROUPS 1024
#define BLOCKS (GROUPS * 25)

__global__ __launch_bounds__(256) void fused_kernel(
    const float* __restrict__ keys, const float* __restrict__ vals,
    const int* __restrict__ maskp,
    float* __restrict__ attn, float* __restrict__ kp, float* __restrict__ ks,
    float* __restrict__ kb, float* __restrict__ vp, float* __restrict__ vs,
    float* __restrict__ vb)
{
    const int tid = threadIdx.x;
    const int b   = blockIdx.x;
    const int g   = b / 25;
    const int rem = b - g * 25;

    if (rem == 0) {
        // ---------------- keys: layout (H, D, S), quantize over D (stride S) ----------
        // 16 B/lane: lane owns a float4 along s. sq = s-quad (16 per tile),
        // dg = d-group (16 groups x 8 rows). Wave reads 4x256B segments per instr.
        const int h  = g >> 7;
        const int s0 = (g & 127) << 6;
        const int sq = tid & 15;
        const int dg = tid >> 4;

        const float* base = keys + (size_t)h * DD * SS + (size_t)dg * 8 * SS + s0 + sq * 4;
        f32x4 v[8];
        f32x4 mn4, mx4;
        mn4.x = mn4.y = mn4.z = mn4.w = 3.0e38f;
        mx4.x = mx4.y = mx4.z = mx4.w = -3.0e38f;
#pragma unroll
        for (int j = 0; j < 8; ++j) {
            v[j] = __builtin_nontemporal_load((const f32x4*)(base + (size_t)j * SS));
            mn4.x = fminf(mn4.x, v[j].x); mx4.x = fmaxf(mx4.x, v[j].x);
            mn4.y = fminf(mn4.y, v[j].y); mx4.y = fmaxf(mx4.y, v[j].y);
            mn4.z = fminf(mn4.z, v[j].z); mx4.z = fmaxf(mx4.z, v[j].z);
            mn4.w = fminf(mn4.w, v[j].w); mx4.w = fmaxf(mx4.w, v[j].w);
        }

        __shared__ f32x4 smn[16][16], smx[16][16];
        __shared__ float ssc[64], sbi[64];
        smn[dg][sq] = mn4;
        smx[dg][sq] = mx4;
        __syncthreads();
        if (tid < 64) {
            // lane sl reduces s = s0+sl over the 16 d-groups. LDS word = gg*64+sl:
            // 2 lanes/bank across the wave -> conflict-free (m136).
            const int q = tid >> 2, cmp = tid & 3;
            float m = 3.0e38f, M = -3.0e38f;
#pragma unroll
            for (int gg = 0; gg < 16; ++gg) {
                m = fminf(m, ((const float*)&smn[gg][q])[cmp]);
                M = fmaxf(M, ((const float*)&smx[gg][q])[cmp]);
            }
            const float scale = (M - m) * (1.0f / 255.0f);  // fp32, matches ref
            ssc[tid] = scale;
            sbi[tid] = m;
            const int o = h * SS + s0 + tid;                 // k_scale/k_bias flat [h][s]
            ks[o] = __half2float(__float2half(scale));       // astype(f16) round-trip, RNE
            kb[o] = __half2float(__float2half(m));
        }
        __syncthreads();
        const f32x4 sc = *(const f32x4*)&ssc[sq * 4];
        const f32x4 bi = *(const f32x4*)&sbi[sq * 4];
        float* ob = kp + (size_t)h * DD * SS + (size_t)dg * 8 * SS + s0 + sq * 4;
#pragma unroll
        for (int j = 0; j < 8; ++j) {
            f32x4 o;
            o.x = rintf((v[j].x - bi.x) / sc.x);
            o.y = rintf((v[j].y - bi.y) / sc.y);
            o.z = rintf((v[j].z - bi.z) / sc.z);
            o.w = rintf((v[j].w - bi.w) / sc.w);
            __builtin_nontemporal_store(o, (f32x4*)(ob + (size_t)j * SS));
        }
    } else if (rem <= 8) {
        // ---------------- values: layout (H, S, D), quantize over contiguous D=128 ----
        const int vbi = g * 8 + (rem - 1);
        const int d4 = tid & 31;          // float4 index within row
        const int rr = tid >> 5;          // 0..7 rows per block
        const int R  = vbi * 8 + rr;      // global row: R = h*8192 + s

        const f32x4 v = __builtin_nontemporal_load((const f32x4*)vals + (size_t)R * 32 + d4);
        float mn = fminf(fminf(v.x, v.y), fminf(v.z, v.w));
        float mx = fmaxf(fmaxf(v.x, v.y), fmaxf(v.z, v.w));
        // butterfly stays inside each 32-lane group on wave64 (xor bits 0..4)
#pragma unroll
        for (int off = 16; off >= 1; off >>= 1) {
            mn = fminf(mn, __shfl_xor(mn, off));
            mx = fmaxf(mx, __shfl_xor(mx, off));
        }
        const float scale = (mx - mn) * (1.0f / 255.0f);
        if (d4 == 0) {
            // v_scale swapaxes(-1,-2) is a no-op on flat memory: both flat [h][s] = [R]
            vs[R] = __half2float(__float2half(scale));
            vb[R] = __half2float(__float2half(mn));
        }
        f32x4 o;
        o.x = rintf((v.x - mn) / scale);
        o.y = rintf((v.y - mn) / scale);
        o.z = rintf((v.z - mn) / scale);
        o.w = rintf((v.w - mn) / scale);
        __builtin_nontemporal_store(o, (f32x4*)vp + (size_t)R * 32 + d4);
    } else {
        // ---------------- attn mask: out[r][c] = (c>r ? -128 : 0) * mask ---------------
        const int a = g * 16 + (rem - 9);          // 0..16383, 1024 float4 per block
        const float hi = (float)(-128 * (*maskp));
        const int base = a * 1024 + tid;
#pragma unroll
        for (int ch = 0; ch < 4; ++ch) {
            const int idx = base + ch * 256;       // float4 index
            const int r = idx >> 11;               // row (2048 float4 per row)
            const int c = (idx & 2047) << 2;       // first col of this float4
            f32x4 v;
            v.x = (c + 0 > r) ? hi : 0.0f;
            v.y = (c + 1 > r) ? hi : 0.0f;
            v.z = (c + 2 > r) ? hi : 0.0f;
            v.w = (c + 3 > r) ? hi : 0.0f;
            __builtin_nontemporal_store(v, (f32x4*)attn + idx);
        }
    }
}

extern "C" void kernel_launch(void* const* d_in, const int* in_sizes, int n_in,
                              void* d_out, int out_size, void* d_ws, size_t ws_size,
                              hipStream_t stream) {
    const float* keys  = (const float*)d_in[0];
    const float* vals  = (const float*)d_in[1];
    const int*   maskp = (const int*)d_in[2];
    // d_in[3] = ids_len, d_in[4] = kv_seq_len — fixed at 8192 (they define output shapes)

    float* out  = (float*)d_out;
    float* attn = out;                       // 8192*8192      = 67108864
    float* kp   = attn + 67108864;           // 8*128*8192     =  8388608
    float* ks   = kp   + 8388608;            // 8*8192         =    65536
    float* kb   = ks   + 65536;              //                     65536
    float* vp   = kb   + 65536;              //                   8388608
    float* vs   = vp   + 8388608;            //                     65536
    float* vb   = vs   + 65536;              //                     65536

    fused_kernel<<<dim3(BLOCKS), dim3(256), 0, stream>>>(keys, vals, maskp,
                                                         attn, kp, ks, kb, vp, vs, vb);
}